// Round 1
// baseline (381.754 us; speedup 1.0000x reference)
//
#include <hip/hip_runtime.h>
#include <hip/hip_fp16.h>

// ---------------------------------------------------------------------------
// MMoE extract-net fused kernels, MI355X (gfx950).
// Strategy: fp16 hi/lo split (3-pass MFMA, ~fp32 accuracy) + transposed
// formulation (batch = MFMA column) so h1/h2 stay in registers via
// shfl_xor(32) half-exchange. Weights pre-arranged into fragment layout by
// a prep kernel. Per-expert outputs -> fp16 scratch, combined by K3.
// ---------------------------------------------------------------------------

#define B_TOT   65536
#define IN_DIM  256
#define HD      64
#define NE      12          // 8 task experts (t*4+e') + 4 shared
// ws fragment region layout, in 16-byte units:
//  A1: [e:12][rt:2][kt:16][hl:2][lane:64]   base 0      (12*4096 units)
//  A2: [e:12][rt:2][kt:4 ][hl:2][lane:64]   base 49152  (12*1024)
//  A3: same as A2                            base 61440
//  AG: [kt:16][hl:2][lane:64]                base 73728  (2048)
#define U_A2 49152
#define U_A3 61440
#define U_AG 73728
#define FRAG_BYTES (75776*16)   // 1,212,416 bytes

typedef _Float16 half8  __attribute__((ext_vector_type(8)));
typedef float    f32x16 __attribute__((ext_vector_type(16)));
typedef float    f32x4  __attribute__((ext_vector_type(4)));
typedef unsigned u32x4  __attribute__((ext_vector_type(4)));

__device__ __forceinline__ unsigned short f2h(float x){
  return __builtin_bit_cast(unsigned short, (_Float16)x);
}
__device__ __forceinline__ float h2f(unsigned short u){
  return (float)__builtin_bit_cast(_Float16, u);
}
__device__ __forceinline__ void split2(float x, unsigned short& h, unsigned short& l){
  h = f2h(x); l = f2h(x - h2f(h));
}
__device__ __forceinline__ half8 FRG(u32x4 u){ return __builtin_bit_cast(half8, u); }
__device__ __forceinline__ f32x16 MF(half8 a, half8 b, f32x16 c){
  return __builtin_amdgcn_mfma_f32_32x32x16_f16(a, b, c, 0, 0, 0);
}
__device__ __forceinline__ f32x16 Z16(){
  f32x16 z;
#pragma unroll
  for (int i=0;i<16;i++) z[i]=0.f;
  return z;
}
// swizzled LDS read of 8 consecutive fp16 of row `row` at byte col offset kb
__device__ __forceinline__ u32x4 lds16(const short* base, int row, int kb){
  return *(const u32x4*)((const char*)base + row*512 + (kb ^ ((row&7)<<4)));
}

// ---------------------------------------------------------------------------
// K0: pre-split weights into hi/lo fp16 MFMA A-fragment layout.
// A-frag (32x32x16): lane holds row=(lane&31), k=(lane>>5)*8 + j, j=0..7.
// ---------------------------------------------------------------------------
__global__ __launch_bounds__(256) void prep(
    const float* __restrict__ Wt1, const float* __restrict__ Ws1,
    const float* __restrict__ Wt2, const float* __restrict__ Ws2,
    const float* __restrict__ Wt3, const float* __restrict__ Ws3,
    const float* __restrict__ Wg,  u32x4* __restrict__ fr){
  int id = blockIdx.x*256 + threadIdx.x;
  if (id >= 37888) return;
  int lane = id & 63;
  int kq   = lane >> 5;      // which k-octet half
  int row  = lane & 31;
  float v[8];
  unsigned ubase;
  if (id < 24576){                                   // A1 = W1^T  [h][k=in]
    int r = id >> 6; int kt = r & 15; int rt = (r>>4)&1; int e = r>>5;
    const float* W = (e<8) ? (Wt1 + (size_t)e*(IN_DIM*HD))
                           : (Ws1 + (size_t)(e-8)*(IN_DIM*HD));
    int h = rt*32 + row;
#pragma unroll
    for (int j=0;j<8;j++){ int k = kt*16 + kq*8 + j; v[j] = W[k*HD + h]; }
    ubase = (unsigned)(e*4096 + ((rt*16+kt)*2)*64 + lane);
  } else if (id < 30720){                            // A2 = W2^T  [h2][k=h1]
    int r = (id-24576) >> 6; int kt = r & 3; int rt = (r>>2)&1; int e = r>>3;
    const float* W = (e<8) ? (Wt2 + (size_t)e*(HD*HD))
                           : (Ws2 + (size_t)(e-8)*(HD*HD));
    int h = rt*32 + row;
#pragma unroll
    for (int j=0;j<8;j++){ int k = kt*16 + kq*8 + j; v[j] = W[k*HD + h]; }
    ubase = (unsigned)(U_A2 + e*1024 + ((rt*4+kt)*2)*64 + lane);
  } else if (id < 36864){                            // A3 = W3^T  [o][k=h2]
    int r = (id-30720) >> 6; int kt = r & 3; int rt = (r>>2)&1; int e = r>>3;
    const float* W = (e<8) ? (Wt3 + (size_t)e*(HD*HD))
                           : (Ws3 + (size_t)(e-8)*(HD*HD));
    int h = rt*32 + row;
#pragma unroll
    for (int j=0;j<8;j++){ int k = kt*16 + kq*8 + j; v[j] = W[k*HD + h]; }
    ubase = (unsigned)(U_A3 + e*1024 + ((rt*4+kt)*2)*64 + lane);
  } else {                                           // AG = Wg^T padded to 32 rows
    int r = (id-36864) >> 6; int kt = r;             // 0..15
    int g = row;                                     // flat logit = t*8+e' (<16)
#pragma unroll
    for (int j=0;j<8;j++){
      int k = kt*16 + kq*8 + j;
      v[j] = (g < 16) ? Wg[(size_t)(g>>3)*(IN_DIM*8) + k*8 + (g&7)] : 0.f;
    }
    ubase = (unsigned)(U_AG + (kt*2)*64 + lane);
  }
  u32x4 uh, ul;
#pragma unroll
  for (int p=0;p<4;p++){
    unsigned short h0,l0,h1,l1;
    split2(v[2*p],h0,l0); split2(v[2*p+1],h1,l1);
    uh[p] = (unsigned)h0 | ((unsigned)h1<<16);
    ul[p] = (unsigned)l0 | ((unsigned)l1<<16);
  }
  fr[ubase]     = uh;
  fr[ubase+64]  = ul;
}

// ---------------------------------------------------------------------------
// K1 helpers
// ---------------------------------------------------------------------------
// epilogue (layers 1/2): bias + relu + fp16 hi/lo split, packed as u32 pairs.
// C/D layout: col=lane&31, row=(j&3)+8*(j>>2)+4*hi  (+32*rt)
__device__ __forceinline__ void epi12(const f32x16& A, const float* bp, int rt, int hi,
                                      unsigned* oh, unsigned* ol){
#pragma unroll
  for (int p=0;p<8;p++){
    const int j0=2*p, j1=2*p+1;
    float v0 = A[j0] + bp[rt*32 + 8*(j0>>2) + 4*hi + (j0&3)];
    float v1 = A[j1] + bp[rt*32 + 8*(j1>>2) + 4*hi + (j1&3)];
    v0 = fmaxf(v0, 0.f); v1 = fmaxf(v1, 0.f);
    unsigned short h0,l0,h1,l1;
    split2(v0,h0,l0); split2(v1,h1,l1);
    oh[p] = (unsigned)h0 | ((unsigned)h1<<16);
    ol[p] = (unsigned)l0 | ((unsigned)l1<<16);
  }
}

// Build B-frag (k=16kt+8*hi + 0..7 of h-dim) from packed C/D pairs via
// half-wave exchange. pk = 8 u32 pairs of one (rt,ct) tile; kl = kt&1.
__device__ __forceinline__ half8 bfrag(const unsigned* pk, int kl, int hi){
  unsigned p0 = pk[4*kl+0], p1 = pk[4*kl+1], p2 = pk[4*kl+2], p3 = pk[4*kl+3];
  unsigned q0 = (unsigned)__shfl_xor((int)p0, 32, 64);
  unsigned q1 = (unsigned)__shfl_xor((int)p1, 32, 64);
  unsigned q2 = (unsigned)__shfl_xor((int)p2, 32, 64);
  unsigned q3 = (unsigned)__shfl_xor((int)p3, 32, 64);
  u32x4 u;
  u.x = hi ? q2 : p0;
  u.y = hi ? q3 : p1;
  u.z = hi ? p2 : q0;
  u.w = hi ? p3 : q1;
  return FRG(u);
}

// layer-3 epilogue: bias (no relu), fp16, assemble o-octets and store raw
// expert output to scratch [b][e][64] fp16 (each half-wave writes 2 octets).
__device__ __forceinline__ void epi3(const f32x16& A, const float* bp, int rt, int ct,
                                     int hi, int li, int e, int lrow0, char* obase){
  unsigned f[8];
#pragma unroll
  for (int p=0;p<8;p++){
    const int j0=2*p, j1=2*p+1;
    float v0 = A[j0] + bp[rt*32 + 8*(j0>>2) + 4*hi + (j0&3)];
    float v1 = A[j1] + bp[rt*32 + 8*(j1>>2) + 4*hi + (j1&3)];
    f[p] = (unsigned)f2h(v0) | ((unsigned)f2h(v1)<<16);
  }
  unsigned g[8];
#pragma unroll
  for (int p=0;p<8;p++) g[p] = (unsigned)__shfl_xor((int)f[p], 32, 64);
  char* ob = obase + ((size_t)(lrow0 + ct*32 + li)*NE + e)*128 + rt*64;
#pragma unroll
  for (int q=0;q<4;q++){
    u32x4 w;
    w.x = hi ? g[2*q]   : f[2*q];
    w.y = hi ? g[2*q+1] : f[2*q+1];
    w.z = hi ? f[2*q]   : g[2*q];
    w.w = hi ? f[2*q+1] : g[2*q+1];
    if ((q>>1) == hi) *(u32x4*)(ob + q*16) = w;
  }
}

#define MM3(ACC, AH, AL, BH, BL) do { \
    ACC = MF(AH,BH,ACC); ACC = MF(AH,BL,ACC); ACC = MF(AL,BH,ACC); } while(0)

// ---------------------------------------------------------------------------
// K1: fused 3-layer expert MLPs + gate logits/softmax. 64 rows per block,
// 4 waves, each wave owns 3 experts (wave 0 also does gates).
// ---------------------------------------------------------------------------
__global__ __launch_bounds__(256,2) void moe(
    const float* __restrict__ X,
    const float* __restrict__ bt1, const float* __restrict__ bs1,
    const float* __restrict__ bt2, const float* __restrict__ bs2,
    const float* __restrict__ bt3, const float* __restrict__ bs3,
    const float* __restrict__ bg,  const u32x4* __restrict__ fr,
    float* __restrict__ gout, char* __restrict__ oout, int crow0){
  __shared__ __align__(16) short Xh[64*256];   // 32 KiB
  __shared__ __align__(16) short Xl[64*256];   // 32 KiB
  const int t = threadIdx.x;
  const int lrow0 = blockIdx.x*64;
  const int grow0 = crow0 + lrow0;

  { // stage X -> hi/lo fp16 LDS, XOR-swizzled by row (bank-conflict fix)
    const int r = t>>2, cq = t&3;
    const float* xp = X + (size_t)(grow0 + r)*IN_DIM + cq*64;
#pragma unroll
    for (int gq=0; gq<8; gq++){
      f32x4 v0 = *(const f32x4*)(xp + gq*8);
      f32x4 v1 = *(const f32x4*)(xp + gq*8 + 4);
      float vv[8] = {v0.x,v0.y,v0.z,v0.w, v1.x,v1.y,v1.z,v1.w};
      u32x4 uh, ul;
#pragma unroll
      for (int p=0;p<4;p++){
        unsigned short h0,l0,h1,l1;
        split2(vv[2*p],h0,l0); split2(vv[2*p+1],h1,l1);
        uh[p] = (unsigned)h0 | ((unsigned)h1<<16);
        ul[p] = (unsigned)l0 | ((unsigned)l1<<16);
      }
      int kb = (cq*64 + gq*8)*2;
      int addr = r*512 + (kb ^ ((r&7)<<4));
      *(u32x4*)((char*)Xh + addr) = uh;
      *(u32x4*)((char*)Xl + addr) = ul;
    }
  }
  __syncthreads();

  const int wave = t>>6, lane = t&63, li = lane&31, hi = lane>>5;

  if (wave == 0){ // ---- gates: logits^T = Wg^T(padded 32) x X^T, then softmax
    f32x16 g0 = Z16(), g1 = Z16();
    const u32x4* AG = fr + U_AG + lane;
#pragma unroll
    for (int kt=0; kt<16; ++kt){
      half8 ah = FRG(AG[(kt*2+0)*64]);
      half8 al = FRG(AG[(kt*2+1)*64]);
      int kb = kt*32 + hi*16;
      half8 xh0 = FRG(lds16(Xh, li,    kb)), xl0 = FRG(lds16(Xl, li,    kb));
      half8 xh1 = FRG(lds16(Xh, li+32, kb)), xl1 = FRG(lds16(Xl, li+32, kb));
      MM3(g0, ah, al, xh0, xl0);
      MM3(g1, ah, al, xh1, xl1);
    }
#pragma unroll
    for (int ct=0; ct<2; ++ct){
      const f32x16& G = ct ? g1 : g0;
      float own[8], par[8];
#pragma unroll
      for (int j=0;j<8;j++) own[j] = G[j] + bg[8*(j>>2) + 4*hi + (j&3)];
#pragma unroll
      for (int j=0;j<8;j++) par[j] = __shfl_xor(own[j], 32, 64);
      float m0 = fmaxf(fmaxf(fmaxf(own[0],own[1]),fmaxf(own[2],own[3])),
                       fmaxf(fmaxf(par[0],par[1]),fmaxf(par[2],par[3])));
      float m1 = fmaxf(fmaxf(fmaxf(own[4],own[5]),fmaxf(own[6],own[7])),
                       fmaxf(fmaxf(par[4],par[5]),fmaxf(par[6],par[7])));
      float eo[8], ep[8];
#pragma unroll
      for (int j=0;j<4;j++){ eo[j]   = __expf(own[j]-m0);   ep[j]   = __expf(par[j]-m0); }
#pragma unroll
      for (int j=4;j<8;j++){ eo[j]   = __expf(own[j]-m1);   ep[j]   = __expf(par[j]-m1); }
      float s0 = eo[0]+eo[1]+eo[2]+eo[3]+ep[0]+ep[1]+ep[2]+ep[3];
      float s1 = eo[4]+eo[5]+eo[6]+eo[7]+ep[4]+ep[5]+ep[6]+ep[7];
      float i0 = 1.f/s0, i1 = 1.f/s1;
      if (hi == 0){   // hi=0 lane's own j0-3 are g0-3; partner j0-3 are g4-7
        float* gp = gout + (size_t)(lrow0 + ct*32 + li)*16;
        f32x4 w;
        w.x=eo[0]*i0; w.y=eo[1]*i0; w.z=eo[2]*i0; w.w=eo[3]*i0; ((f32x4*)gp)[0]=w;
        w.x=ep[0]*i0; w.y=ep[1]*i0; w.z=ep[2]*i0; w.w=ep[3]*i0; ((f32x4*)gp)[1]=w;
        w.x=eo[4]*i1; w.y=eo[5]*i1; w.z=eo[6]*i1; w.w=eo[7]*i1; ((f32x4*)gp)[2]=w;
        w.x=ep[4]*i1; w.y=ep[5]*i1; w.z=ep[6]*i1; w.w=ep[7]*i1; ((f32x4*)gp)[3]=w;
      }
    }
  }

  unsigned opkh[2][2][8], opkl[2][2][8];   // [rt][ct][pair] packed hi/lo fp16
#pragma unroll 1
  for (int ei=0; ei<3; ++ei){
    const int e = wave*3 + ei;
    // -------- layer 1: h1^T = W1^T x X^T  (K=256)
    f32x16 a00=Z16(), a01=Z16(), a10=Z16(), a11=Z16();
    const u32x4* A1 = fr + e*4096 + lane;
#pragma unroll
    for (int kt=0; kt<16; ++kt){
      half8 ah0 = FRG(A1[( kt     *2+0)*64]);
      half8 al0 = FRG(A1[( kt     *2+1)*64]);
      half8 ah1 = FRG(A1[((16+kt) *2+0)*64]);
      half8 al1 = FRG(A1[((16+kt) *2+1)*64]);
      int kb = kt*32 + hi*16;
      half8 xh0 = FRG(lds16(Xh, li,    kb)), xl0 = FRG(lds16(Xl, li,    kb));
      half8 xh1 = FRG(lds16(Xh, li+32, kb)), xl1 = FRG(lds16(Xl, li+32, kb));
      MM3(a00, ah0, al0, xh0, xl0);
      MM3(a01, ah0, al0, xh1, xl1);
      MM3(a10, ah1, al1, xh0, xl0);
      MM3(a11, ah1, al1, xh1, xl1);
    }
    const float* b1 = (e<8)? bt1+e*64 : bs1+(e-8)*64;
    epi12(a00,b1,0,hi,opkh[0][0],opkl[0][0]);
    epi12(a01,b1,0,hi,opkh[0][1],opkl[0][1]);
    epi12(a10,b1,1,hi,opkh[1][0],opkl[1][0]);
    epi12(a11,b1,1,hi,opkh[1][1],opkl[1][1]);
    // -------- layer 2: h2^T = W2^T x h1^T  (K=64, B from registers)
    f32x16 c00=Z16(), c01=Z16(), c10=Z16(), c11=Z16();
    const u32x4* A2 = fr + U_A2 + e*1024 + lane;
#pragma unroll
    for (int kt=0; kt<4; ++kt){
      half8 ah0 = FRG(A2[( kt    *2+0)*64]);
      half8 al0 = FRG(A2[( kt    *2+1)*64]);
      half8 ah1 = FRG(A2[((4+kt) *2+0)*64]);
      half8 al1 = FRG(A2[((4+kt) *2+1)*64]);
      const int rs = kt>>1, kl = kt&1;
      half8 bh0 = bfrag(opkh[rs][0], kl, hi), bl0 = bfrag(opkl[rs][0], kl, hi);
      half8 bh1 = bfrag(opkh[rs][1], kl, hi), bl1 = bfrag(opkl[rs][1], kl, hi);
      MM3(c00, ah0, al0, bh0, bl0);
      MM3(c01, ah0, al0, bh1, bl1);
      MM3(c10, ah1, al1, bh0, bl0);
      MM3(c11, ah1, al1, bh1, bl1);
    }
    const float* b2 = (e<8)? bt2+e*64 : bs2+(e-8)*64;
    epi12(c00,b2,0,hi,opkh[0][0],opkl[0][0]);
    epi12(c01,b2,0,hi,opkh[0][1],opkl[0][1]);
    epi12(c10,b2,1,hi,opkh[1][0],opkl[1][0]);
    epi12(c11,b2,1,hi,opkh[1][1],opkl[1][1]);
    // -------- layer 3: o^T = W3^T x h2^T  (K=64)
    f32x16 d00=Z16(), d01=Z16(), d10=Z16(), d11=Z16();
    const u32x4* A3 = fr + U_A3 + e*1024 + lane;
#pragma unroll
    for (int kt=0; kt<4; ++kt){
      half8 ah0 = FRG(A3[( kt    *2+0)*64]);
      half8 al0 = FRG(A3[( kt    *2+1)*64]);
      half8 ah1 = FRG(A3[((4+kt) *2+0)*64]);
      half8 al1 = FRG(A3[((4+kt) *2+1)*64]);
      const int rs = kt>>1, kl = kt&1;
      half8 bh0 = bfrag(opkh[rs][0], kl, hi), bl0 = bfrag(opkl[rs][0], kl, hi);
      half8 bh1 = bfrag(opkh[rs][1], kl, hi), bl1 = bfrag(opkl[rs][1], kl, hi);
      MM3(d00, ah0, al0, bh0, bl0);
      MM3(d01, ah0, al0, bh1, bl1);
      MM3(d10, ah1, al1, bh0, bl0);
      MM3(d11, ah1, al1, bh1, bl1);
    }
    const float* b3 = (e<8)? bt3+e*64 : bs3+(e-8)*64;
    epi3(d00,b3,0,0,hi,li,e,lrow0,oout);
    epi3(d01,b3,0,1,hi,li,e,lrow0,oout);
    epi3(d10,b3,1,0,hi,li,e,lrow0,oout);
    epi3(d11,b3,1,1,hi,li,e,lrow0,oout);
  }
}

// ---------------------------------------------------------------------------
// K3: gated combine.  out[b][t][o] = sum_e gate * o_e[b][o]
// ---------------------------------------------------------------------------
__device__ __forceinline__ float2 uph(unsigned u){
  __half2 h = __builtin_bit_cast(__half2, u);
  return __half22float2(h);
}
__global__ __launch_bounds__(256) void comb(
    const u32x4* __restrict__ o, const float* __restrict__ g,
    float* __restrict__ out, int rows, int crow0){
  int tid = blockIdx.x*256 + threadIdx.x;
  if (tid >= rows*4) return;
  int bl = tid>>2, quad = tid&3;
  const u32x4* ob = o + (size_t)bl*96 + quad*2;   // [b][e][64] fp16
  const f32x4* gp = (const f32x4*)(g + (size_t)bl*16);
  f32x4 G0=gp[0], G1=gp[1], G2=gp[2], G3=gp[3];
  float gt[16] = {G0.x,G0.y,G0.z,G0.w, G1.x,G1.y,G1.z,G1.w,
                  G2.x,G2.y,G2.z,G2.w, G3.x,G3.y,G3.z,G3.w};
  float s0[16], s1[16];
#pragma unroll
  for (int i=0;i<16;i++){ s0[i]=0.f; s1[i]=0.f; }
#pragma unroll
  for (int e=0;e<12;e++){
    u32x4 u0 = ob[e*8], u1 = ob[e*8+1];
    float w0 = (e<4) ? gt[e]   : ((e>=8) ? gt[e-4] : 0.f);
    float w1 = (e>=4 && e<8) ? gt[e+4] : ((e>=8) ? gt[e+4] : 0.f);
    float v[16];
#pragma unroll
    for (int p=0;p<4;p++){
      float2 f0 = uph(u0[p]); v[2*p]   = f0.x; v[2*p+1]   = f0.y;
      float2 f1 = uph(u1[p]); v[8+2*p] = f1.x; v[8+2*p+1] = f1.y;
    }
#pragma unroll
    for (int i=0;i<16;i++){ s0[i] += w0*v[i]; s1[i] += w1*v[i]; }
  }
  size_t b = (size_t)crow0 + bl;
  float* op = out + b*128 + quad*16;
#pragma unroll
  for (int p=0;p<4;p++){
    f32x4 w; w.x=s0[4*p]; w.y=s0[4*p+1]; w.z=s0[4*p+2]; w.w=s0[4*p+3];
    *(f32x4*)(op + 4*p) = w;
  }
#pragma unroll
  for (int p=0;p<4;p++){
    f32x4 w; w.x=s1[4*p]; w.y=s1[4*p+1]; w.z=s1[4*p+2]; w.w=s1[4*p+3];
    *(f32x4*)(op + 64 + 4*p) = w;
  }
}

// ---------------------------------------------------------------------------
extern "C" void kernel_launch(void* const* d_in, const int* in_sizes, int n_in,
                              void* d_out, int out_size, void* d_ws, size_t ws_size,
                              hipStream_t stream){
  const float* X   = (const float*)d_in[0];
  const float* Wt1 = (const float*)d_in[1];
  const float* bt1 = (const float*)d_in[2];
  const float* Wt2 = (const float*)d_in[3];
  const float* bt2 = (const float*)d_in[4];
  const float* Wt3 = (const float*)d_in[5];
  const float* bt3 = (const float*)d_in[6];
  const float* Ws1 = (const float*)d_in[7];
  const float* bs1 = (const float*)d_in[8];
  const float* Ws2 = (const float*)d_in[9];
  const float* bs2 = (const float*)d_in[10];
  const float* Ws3 = (const float*)d_in[11];
  const float* bs3 = (const float*)d_in[12];
  const float* Wg  = (const float*)d_in[13];
  const float* bg  = (const float*)d_in[14];

  char*  ws = (char*)d_ws;
  u32x4* fr = (u32x4*)ws;
  size_t avail = ws_size > (size_t)FRAG_BYTES ? ws_size - FRAG_BYTES : 0;
  // per-row scratch: 12*64*2 B (o, fp16) + 16*4 B (gates) = 1600 B
  int chunk = B_TOT;
  while (chunk > 64 && (size_t)chunk*1600 > avail) chunk >>= 1;

  hipLaunchKernelGGL(prep, dim3(148), dim3(256), 0, stream,
                     Wt1, Ws1, Wt2, Ws2, Wt3, Ws3, Wg, fr);
  for (int r0 = 0; r0 < B_TOT; r0 += chunk){
    float* gts = (float*)(ws + FRAG_BYTES);
    char*  ob  = ws + FRAG_BYTES + (size_t)chunk*64;   // gates = chunk*64 B
    hipLaunchKernelGGL(moe, dim3(chunk/64), dim3(256), 0, stream,
                       X, bt1, bs1, bt2, bs2, bt3, bs3, bg, fr, gts, ob, r0);
    hipLaunchKernelGGL(comb, dim3((chunk*4+255)/256), dim3(256), 0, stream,
                       (const u32x4*)ob, gts, (float*)d_out, chunk, r0);
  }
}